// Round 3
// baseline (441.645 us; speedup 1.0000x reference)
//
#include <hip/hip_runtime.h>

#define DEV __device__ __forceinline__

typedef float  f32x4  __attribute__((ext_vector_type(4)));
typedef __bf16 bf16x8 __attribute__((ext_vector_type(8)));

DEV unsigned short f2bf(float f) {
  unsigned u = __float_as_uint(f);
  u += 0x7fffu + ((u >> 16) & 1u);           // round-to-nearest-even
  return (unsigned short)(u >> 16);
}
DEV float bf2f(unsigned short v) { return __uint_as_float(((unsigned)v) << 16); }

DEV void cp16(const void* g, void* l) {      // async global->LDS, 16B/lane
  __builtin_amdgcn_global_load_lds((const __attribute__((address_space(1))) void*)g,
                                   (__attribute__((address_space(3))) void*)l, 16, 0, 0);
}

// ---------------- prep: weights fp32->bf16 + qkv bias assembly --------------
__global__ __launch_bounds__(256) void prep_kernel(
    const float* __restrict__ qkv_w, const float* __restrict__ proj_w,
    const float* __restrict__ q_bias, const float* __restrict__ v_bias,
    unsigned short* __restrict__ wq, unsigned short* __restrict__ wp,
    float* __restrict__ qkvb)
{
  int gid = blockIdx.x * 256 + threadIdx.x;     // 1024 blocks -> 262144 = 196608+65536
  if (gid < 196608) wq[gid] = f2bf(qkv_w[gid]);
  else              wp[gid - 196608] = f2bf(proj_w[gid - 196608]);
  if (gid < 768)
    qkvb[gid] = (gid < 256) ? q_bias[gid] : ((gid < 512) ? 0.f : v_bias[gid - 512]);
}

// ---------------- CPB MLP: table16[r][h] = 16*sigmoid(mlp(tab[r])) ----------
__global__ __launch_bounds__(64) void cpb_mlp(
    const float* __restrict__ tab, const float* __restrict__ w1,
    const float* __restrict__ b1, const float* __restrict__ w2,
    float* __restrict__ table16)
{
  int r = blockIdx.x;            // 169 rows
  int t = threadIdx.x;           // 64 lanes
  float x0 = tab[r * 2 + 0], x1 = tab[r * 2 + 1];
  float part[8];
#pragma unroll
  for (int h = 0; h < 8; ++h) part[h] = 0.f;
  for (int j = t; j < 512; j += 64) {
    float hv = fmaxf(w1[j * 2 + 0] * x0 + w1[j * 2 + 1] * x1 + b1[j], 0.f);
#pragma unroll
    for (int h = 0; h < 8; ++h) part[h] += hv * w2[h * 512 + j];
  }
#pragma unroll
  for (int h = 0; h < 8; ++h) {
    float v = part[h];
    for (int off = 32; off > 0; off >>= 1) v += __shfl_down(v, off, 64);
    if (t == 0) table16[r * 8 + h] = 16.f / (1.f + expf(-v));
  }
}

// -------- bias64[h][i][j] (8x64x64) and mask64[w][i][j] (64x64x64), 0-padded
__global__ __launch_bounds__(256) void bmb(
    const float* __restrict__ t16, const int* __restrict__ ridx,
    const float* __restrict__ mask, float* __restrict__ bias64,
    float* __restrict__ mask64)
{
  int gid = blockIdx.x * 256 + threadIdx.x;   // 1152 blocks = 294912 = 32768 + 262144
  int p = gid & 4095, i = p >> 6, j = p & 63;
  bool valid = (i < 49) && (j < 49);
  if (gid < 32768) {
    int h = gid >> 12;
    bias64[gid] = valid ? t16[ridx[i * 49 + j] * 8 + h] : 0.f;
  } else {
    int g2 = gid - 32768;
    int w = g2 >> 12;
    mask64[g2] = valid ? mask[w * 2401 + i * 49 + j] : 0.f;
  }
}

// ---------------- QKV GEMM: fp32 A, head-packed bf16 output -----------------
// qkv_p[b][h][s][tok][32]  (s in {q,k,v});  addr = ((b*8+h)*3+s)*1568 + tok*32 + d
// 128x128 tile, BK=64, XCD-swizzled 1D grid (8 x 98 row-tiles x 6 col-tiles).
__global__ __launch_bounds__(256) void gemm_qkv(
    const float* __restrict__ X, const unsigned short* __restrict__ W,
    const float* __restrict__ bias, unsigned short* __restrict__ qkv)
{
  __shared__ __align__(1024) unsigned short sA[128 * 64];
  __shared__ __align__(1024) unsigned short sB[128 * 64];
  const int t = threadIdx.x, w = t >> 6, l = t & 63, quad = l >> 4, l15 = l & 15;
  const int idx = blockIdx.x;
  const int x8 = idx & 7, local = idx >> 3;
  const int my = x8 * 98 + local / 6, bnb = local % 6;
  const int bm = my * 128, bn = bnb * 128;
  const int wm = (w >> 1) * 64, wn = (w & 1) * 64;
  const int arow = t >> 1, ahalf = t & 1;    // A staging: 2 threads per row
  const int srow = t >> 3, sch = t & 7;      // B staging (cp16)

  f32x4 acc[4][4] = {};
#pragma unroll 1
  for (int kt = 0; kt < 4; ++kt) {
    const int k0 = kt << 6;
    if (kt) __syncthreads();
#pragma unroll
    for (int i = 0; i < 4; ++i) {            // B: async 16B direct-to-LDS
      const int row = i * 32 + srow;
      const int sc  = sch ^ (srow & 7);
      cp16(W + (size_t)(bn + row) * 256 + k0 + sc * 8, sB + (i * 256 + w * 64) * 8);
    }
    {                                         // A: fp32 -> bf16 -> ds_write_b128
      const float* ap = X + (size_t)(bm + arow) * 256 + k0 + ahalf * 32;
#pragma unroll
      for (int c = 0; c < 4; ++c) {
        float4 f0 = *(const float4*)(ap + c * 8);
        float4 f1 = *(const float4*)(ap + c * 8 + 4);
        uint4 u;
        u.x = f2bf(f0.x) | ((unsigned)f2bf(f0.y) << 16);
        u.y = f2bf(f0.z) | ((unsigned)f2bf(f0.w) << 16);
        u.z = f2bf(f1.x) | ((unsigned)f2bf(f1.y) << 16);
        u.w = f2bf(f1.z) | ((unsigned)f2bf(f1.w) << 16);
        const int cb = ahalf * 4 + c;
        *(uint4*)&sA[arow * 64 + ((cb ^ (arow & 7)) * 8)] = u;
      }
    }
    __syncthreads();
#pragma unroll
    for (int kk = 0; kk < 2; ++kk) {
      bf16x8 af[4], bfr[4];
#pragma unroll
      for (int mt = 0; mt < 4; ++mt)
        af[mt] = *(const bf16x8*)&sA[(wm + mt * 16 + l15) * 64 + (((4 * kk + quad) ^ (l15 & 7)) * 8)];
#pragma unroll
      for (int nt = 0; nt < 4; ++nt)
        bfr[nt] = *(const bf16x8*)&sB[(wn + nt * 16 + l15) * 64 + (((4 * kk + quad) ^ (l15 & 7)) * 8)];
#pragma unroll
      for (int mt = 0; mt < 4; ++mt)
#pragma unroll
        for (int nt = 0; nt < 4; ++nt)
          acc[mt][nt] = __builtin_amdgcn_mfma_f32_16x16x32_bf16(af[mt], bfr[nt], acc[mt][nt], 0, 0, 0);
    }
  }
  // epilogue: per-lane rows -> (window b, token tok) via magic div by 49
  unsigned bq[16]; int tq[16];
#pragma unroll
  for (int mt = 0; mt < 4; ++mt)
#pragma unroll
    for (int r = 0; r < 4; ++r) {
      const int row = bm + wm + mt * 16 + quad * 4 + r;
      const unsigned bb = (unsigned)(((unsigned long long)row * 87652394ull) >> 32);
      bq[mt * 4 + r] = bb;
      tq[mt * 4 + r] = row - (int)bb * 49;
    }
#pragma unroll
  for (int nt = 0; nt < 4; ++nt) {
    const int col0 = bn + wn + nt * 16;           // multiple of 16 -> s,h,dbase uniform
    const int s = col0 >> 8, h = (col0 >> 5) & 7, dbase = col0 & 31;
    const int d = dbase + l15;
    const float bv = bias[col0 + l15];
#pragma unroll
    for (int mt = 0; mt < 4; ++mt)
#pragma unroll
      for (int r = 0; r < 4; ++r) {
        const unsigned bb = bq[mt * 4 + r];
        const int tok = tq[mt * 4 + r];
        qkv[(size_t)((bb * 8u + h) * 3u + s) * 1568 + tok * 32 + d] =
            f2bf(acc[mt][nt][r] + bv);
      }
  }
}

// ---------------- MFMA window attention v2: head-packed input ---------------
// Frags straight from global (coalesced 1KB/wave loads); norms from frags;
// P via swizzled LDS; V^T staged from 64B-stride reads.
__global__ __launch_bounds__(256) void attn2(
    const unsigned short* __restrict__ qkv, const float* __restrict__ logit_scale,
    const float* __restrict__ bias64, const float* __restrict__ mask64,
    unsigned short* __restrict__ aout)
{
  __shared__ __align__(1024) char smem[4 * 12544];
  const int w = threadIdx.x >> 6, l = threadIdx.x & 63, quad = l >> 4, l15 = l & 15;
  const int flat = blockIdx.x * 4 + w;
  const int b = flat >> 3, h = flat & 7;
  char* my = smem + w * 12544;
  unsigned short* vT = (unsigned short*)my;            // [32][64] bf16, swizzled, 4 KB
  unsigned short* P  = (unsigned short*)(my + 4096);   // [64][64] bf16, swizzled, 8 KB
  float* rk = (float*)(my + 12288);                    // 64 f32

  const unsigned short* qb = qkv + (size_t)flat * 4704;
  const unsigned short* kb = qb + 1568;
  const unsigned short* vb = qb + 3136;

  // ---- fragment loads: lane reads 16B at tok*64B + quad*16B -> 1KB/wave
  bf16x8 kf[4], qf[4];
#pragma unroll
  for (int mt = 0; mt < 4; ++mt) kf[mt] = *(const bf16x8*)(kb + (mt * 16 + l15) * 32 + quad * 8);
#pragma unroll
  for (int nt = 0; nt < 4; ++nt) qf[nt] = *(const bf16x8*)(qb + (nt * 16 + l15) * 32 + quad * 8);

  // ---- norms from frags (sumsq over 8 in-lane dims, reduce across quads)
  const float scale = __expf(fminf(logit_scale[h], 4.60517019f));
  float rqv[4];
#pragma unroll
  for (int nt = 0; nt < 4; ++nt) {
    float s = 0.f;
#pragma unroll
    for (int d = 0; d < 8; ++d) { float f = (float)qf[nt][d]; s += f * f; }
    s += __shfl_xor(s, 16, 64); s += __shfl_xor(s, 32, 64);
    rqv[nt] = scale / fmaxf(sqrtf(s), 1e-12f);          // for token i = nt*16+l15
  }
#pragma unroll
  for (int mt = 0; mt < 4; ++mt) {
    float s = 0.f;
#pragma unroll
    for (int d = 0; d < 8; ++d) { float f = (float)kf[mt][d]; s += f * f; }
    s += __shfl_xor(s, 16, 64); s += __shfl_xor(s, 32, 64);
    if (quad == 0) rk[mt * 16 + l15] = 1.f / fmaxf(sqrtf(s), 1e-12f);
  }

  // ---- V^T stage (zero-pad tokens 49..63)
  if (l < 49) {
    unsigned short vv[32];
#pragma unroll
    for (int c = 0; c < 4; ++c) *(uint4*)&vv[c * 8] = *(const uint4*)(vb + l * 32 + c * 8);
#pragma unroll
    for (int d = 0; d < 32; ++d)
      vT[d * 64 + (((l >> 3) ^ (d & 7)) << 3) + (l & 7)] = vv[d];
  } else {
#pragma unroll
    for (int d = 0; d < 32; ++d)
      vT[d * 64 + (((l >> 3) ^ (d & 7)) << 3) + (l & 7)] = 0;
  }
  __syncthreads();

  // ---- S^T[j][i] = K . Q^T
  f32x4 acc[4][4] = {};
#pragma unroll
  for (int mt = 0; mt < 4; ++mt)
#pragma unroll
    for (int nt = 0; nt < 4; ++nt)
      acc[mt][nt] = __builtin_amdgcn_mfma_f32_16x16x32_bf16(kf[mt], qf[nt], acc[mt][nt], 0, 0, 0);

  // ---- softmax (token i = nt*16+l15), store P = p/sum to LDS (bf16, swizzled)
  const float* bh = bias64 + (size_t)h * 4096;
  const float* mw = mask64 + (size_t)(b & 63) * 4096;
#pragma unroll
  for (int nt = 0; nt < 4; ++nt) {
    const int i = nt * 16 + l15;
    const float rqi = rqv[nt];
    float s[4][4];
    float mx = -1e30f;
#pragma unroll
    for (int mt = 0; mt < 4; ++mt) {
      const int jb = mt * 16 + quad * 4;
      const f32x4 b4  = *(const f32x4*)(bh + i * 64 + jb);
      const f32x4 m4  = *(const f32x4*)(mw + i * 64 + jb);
      const f32x4 rk4 = *(const f32x4*)(rk + jb);
#pragma unroll
      for (int r = 0; r < 4; ++r) {
        float sv = acc[mt][nt][r] * (rqi * rk4[r]) + b4[r] + m4[r];
        sv = (jb + r < 49) ? sv : -1e30f;
        s[mt][r] = sv;
        mx = fmaxf(mx, sv);
      }
    }
    mx = fmaxf(mx, __shfl_xor(mx, 16, 64));
    mx = fmaxf(mx, __shfl_xor(mx, 32, 64));
    float sum = 0.f;
    float p[4][4];
#pragma unroll
    for (int mt = 0; mt < 4; ++mt)
#pragma unroll
      for (int r = 0; r < 4; ++r) {
        float pv = __expf(s[mt][r] - mx);
        p[mt][r] = pv; sum += pv;
      }
    sum += __shfl_xor(sum, 16, 64);
    sum += __shfl_xor(sum, 32, 64);
    const float rs = 1.f / sum;
#pragma unroll
    for (int mt = 0; mt < 4; ++mt) {
      unsigned d0 = f2bf(p[mt][0] * rs) | ((unsigned)f2bf(p[mt][1] * rs) << 16);
      unsigned d1 = f2bf(p[mt][2] * rs) | ((unsigned)f2bf(p[mt][3] * rs) << 16);
      const int c = 2 * mt + (quad >> 1);
      uint2 uv; uv.x = d0; uv.y = d1;
      *(uint2*)((char*)P + i * 128 + ((c ^ (i & 7)) * 16) + (quad & 1) * 8) = uv;
    }
  }
  __syncthreads();

  // ---- O^T[d][i] = V^T . P^T
  f32x4 oacc[2][4] = {};
#pragma unroll
  for (int kk = 0; kk < 2; ++kk) {
    bf16x8 vf[2], pf[4];
#pragma unroll
    for (int mt = 0; mt < 2; ++mt)
      vf[mt] = *(const bf16x8*)((char*)vT + (mt * 16 + l15) * 128 + (((4 * kk + quad) ^ (l15 & 7)) * 16));
#pragma unroll
    for (int nt = 0; nt < 4; ++nt)
      pf[nt] = *(const bf16x8*)((char*)P + (nt * 16 + l15) * 128 + (((4 * kk + quad) ^ (l15 & 7)) * 16));
#pragma unroll
    for (int mt = 0; mt < 2; ++mt)
#pragma unroll
      for (int nt = 0; nt < 4; ++nt)
        oacc[mt][nt] = __builtin_amdgcn_mfma_f32_16x16x32_bf16(vf[mt], pf[nt], oacc[mt][nt], 0, 0, 0);
  }

  // ---- store O (col=token=l15+16nt, row=d=quad*4+r+16mt)
#pragma unroll
  for (int nt = 0; nt < 4; ++nt) {
    const int tok = nt * 16 + l15;
    if (tok < 49) {
      unsigned short* op = aout + (size_t)(b * 49 + tok) * 256 + h * 32;
#pragma unroll
      for (int mt = 0; mt < 2; ++mt) {
        unsigned u0 = f2bf(oacc[mt][nt][0]) | ((unsigned)f2bf(oacc[mt][nt][1]) << 16);
        unsigned u1 = f2bf(oacc[mt][nt][2]) | ((unsigned)f2bf(oacc[mt][nt][3]) << 16);
        uint2 uv; uv.x = u0; uv.y = u1;
        *(uint2*)(op + mt * 16 + quad * 4) = uv;
      }
    }
  }
}

// ---------------- proj GEMM (bf16 A via cp16, fp32 out) ---------------------
template <bool OBF16>
__global__ __launch_bounds__(256) void gemm128(
    const unsigned short* __restrict__ A, const unsigned short* __restrict__ W,
    const float* __restrict__ bias, void* __restrict__ Yp, int N, int K)
{
  __shared__ __align__(1024) unsigned short sA[128 * 64];
  __shared__ __align__(1024) unsigned short sB[128 * 64];
  const int t = threadIdx.x, w = t >> 6, l = t & 63, quad = l >> 4, l15 = l & 15;
  const int bm = blockIdx.y * 128, bn = blockIdx.x * 128;
  const int wm = (w >> 1) * 64, wn = (w & 1) * 64;
  const int srow = t >> 3, sch = t & 7;

  f32x4 acc[4][4] = {};
  const int KT = K >> 6;
  for (int kt = 0; kt < KT; ++kt) {
    const int k0 = kt << 6;
    if (kt) __syncthreads();
#pragma unroll
    for (int i = 0; i < 4; ++i) {
      const int row = i * 32 + srow;
      const int sc  = sch ^ (srow & 7);
      cp16(A + (size_t)(bm + row) * K + k0 + sc * 8, sA + (i * 256 + w * 64) * 8);
      cp16(W + (size_t)(bn + row) * K + k0 + sc * 8, sB + (i * 256 + w * 64) * 8);
    }
    __syncthreads();
#pragma unroll
    for (int kk = 0; kk < 2; ++kk) {
      bf16x8 af[4], bfr[4];
#pragma unroll
      for (int mt = 0; mt < 4; ++mt)
        af[mt] = *(const bf16x8*)&sA[(wm + mt * 16 + l15) * 64 + (((4 * kk + quad) ^ (l15 & 7)) * 8)];
#pragma unroll
      for (int nt = 0; nt < 4; ++nt)
        bfr[nt] = *(const bf16x8*)&sB[(wn + nt * 16 + l15) * 64 + (((4 * kk + quad) ^ (l15 & 7)) * 8)];
#pragma unroll
      for (int mt = 0; mt < 4; ++mt)
#pragma unroll
        for (int nt = 0; nt < 4; ++nt)
          acc[mt][nt] = __builtin_amdgcn_mfma_f32_16x16x32_bf16(af[mt], bfr[nt], acc[mt][nt], 0, 0, 0);
    }
  }
#pragma unroll
  for (int nt = 0; nt < 4; ++nt) {
    const int col = bn + wn + nt * 16 + l15;
    const float bv = bias[col];
#pragma unroll
    for (int mt = 0; mt < 4; ++mt) {
#pragma unroll
      for (int r = 0; r < 4; ++r) {
        const int row = bm + wm + mt * 16 + quad * 4 + r;
        float v = acc[mt][nt][r] + bv;
        if constexpr (OBF16) ((unsigned short*)Yp)[(size_t)row * N + col] = f2bf(v);
        else                 ((float*)Yp)[(size_t)row * N + col] = v;
      }
    }
  }
}

// ---------------------------------------------------------------------------
extern "C" void kernel_launch(void* const* d_in, const int* in_sizes, int n_in,
                              void* d_out, int out_size, void* d_ws, size_t ws_size,
                              hipStream_t stream) {
  const float* x           = (const float*)d_in[0];
  const float* mask        = (const float*)d_in[1];
  const float* qkv_w       = (const float*)d_in[2];
  const float* q_bias      = (const float*)d_in[3];
  const float* v_bias      = (const float*)d_in[4];
  const float* logit_scale = (const float*)d_in[5];
  const float* cpb_w1      = (const float*)d_in[6];
  const float* cpb_b1      = (const float*)d_in[7];
  const float* cpb_w2      = (const float*)d_in[8];
  const float* proj_w      = (const float*)d_in[9];
  const float* proj_b      = (const float*)d_in[10];
  const float* rel_tab     = (const float*)d_in[11];
  const int*   rel_idx     = (const int*)d_in[12];
  float*       out         = (float*)d_out;

  char* ws = (char*)d_ws;
  unsigned short* qkvp    = (unsigned short*)(ws + 0);          // 154140672 (head-packed)
  unsigned short* aows    = (unsigned short*)(ws + 154140672);  // 51380224
  unsigned short* wq      = (unsigned short*)(ws + 205520896);  // 393216
  unsigned short* wp      = (unsigned short*)(ws + 205914112);  // 131072
  float*          qkvb    = (float*)(ws + 206045184);           // 3072
  float*          table16 = (float*)(ws + 206048256);           // 5632
  float*          bias64  = (float*)(ws + 206053888);           // 131072
  float*          mask64  = (float*)(ws + 206184960);           // 1048576
  // end: 207233536 (same footprint as round 2)

  prep_kernel<<<1024, 256, 0, stream>>>(qkv_w, proj_w, q_bias, v_bias, wq, wp, qkvb);
  cpb_mlp<<<169, 64, 0, stream>>>(rel_tab, cpb_w1, cpb_b1, cpb_w2, table16);
  bmb<<<1152, 256, 0, stream>>>(table16, rel_idx, mask, bias64, mask64);
  // QKV GEMM: fp32 x directly, head-packed bf16 out (xcvt kernel deleted)
  gemm_qkv<<<4704, 256, 0, stream>>>(x, wq, qkvb, qkvp);
  attn2<<<4096, 256, 0, stream>>>(qkvp, logit_scale, bias64, mask64, aows);
  // proj GEMM: [100352,256]bf16 @ [256,256]^T -> fp32 out
  gemm128<false><<<dim3(2, 784), 256, 0, stream>>>(aows, wp, proj_b, out, 256, 256);
}

// Round 4
// 413.913 us; speedup vs baseline: 1.0670x; 1.0670x over previous
//
#include <hip/hip_runtime.h>

#define DEV __device__ __forceinline__

typedef float  f32x4  __attribute__((ext_vector_type(4)));
typedef __bf16 bf16x8 __attribute__((ext_vector_type(8)));

DEV unsigned short f2bf(float f) {
  unsigned u = __float_as_uint(f);
  u += 0x7fffu + ((u >> 16) & 1u);           // round-to-nearest-even
  return (unsigned short)(u >> 16);
}
DEV float bf2f(unsigned short v) { return __uint_as_float(((unsigned)v) << 16); }

DEV void cp16(const void* g, void* l) {      // async global->LDS, 16B/lane
  __builtin_amdgcn_global_load_lds((const __attribute__((address_space(1))) void*)g,
                                   (__attribute__((address_space(3))) void*)l, 16, 0, 0);
}

// ---------------- prep: weights fp32->bf16 + qkv bias assembly --------------
__global__ __launch_bounds__(256) void prep_kernel(
    const float* __restrict__ qkv_w, const float* __restrict__ proj_w,
    const float* __restrict__ q_bias, const float* __restrict__ v_bias,
    unsigned short* __restrict__ wq, unsigned short* __restrict__ wp,
    float* __restrict__ qkvb)
{
  int gid = blockIdx.x * 256 + threadIdx.x;     // 1024 blocks -> 262144 = 196608+65536
  if (gid < 196608) wq[gid] = f2bf(qkv_w[gid]);
  else              wp[gid - 196608] = f2bf(proj_w[gid - 196608]);
  if (gid < 768)
    qkvb[gid] = (gid < 256) ? q_bias[gid] : ((gid < 512) ? 0.f : v_bias[gid - 512]);
}

// ---------------- CPB MLP: table16[r][h] = 16*sigmoid(mlp(tab[r])) ----------
__global__ __launch_bounds__(64) void cpb_mlp(
    const float* __restrict__ tab, const float* __restrict__ w1,
    const float* __restrict__ b1, const float* __restrict__ w2,
    float* __restrict__ table16)
{
  int r = blockIdx.x;            // 169 rows
  int t = threadIdx.x;           // 64 lanes
  float x0 = tab[r * 2 + 0], x1 = tab[r * 2 + 1];
  float part[8];
#pragma unroll
  for (int h = 0; h < 8; ++h) part[h] = 0.f;
  for (int j = t; j < 512; j += 64) {
    float hv = fmaxf(w1[j * 2 + 0] * x0 + w1[j * 2 + 1] * x1 + b1[j], 0.f);
#pragma unroll
    for (int h = 0; h < 8; ++h) part[h] += hv * w2[h * 512 + j];
  }
#pragma unroll
  for (int h = 0; h < 8; ++h) {
    float v = part[h];
    for (int off = 32; off > 0; off >>= 1) v += __shfl_down(v, off, 64);
    if (t == 0) table16[r * 8 + h] = 16.f / (1.f + expf(-v));
  }
}

// -------- bias64[h][i][j] (8x64x64) and mask64[w][i][j] (64x64x64), 0-padded
__global__ __launch_bounds__(256) void bmb(
    const float* __restrict__ t16, const int* __restrict__ ridx,
    const float* __restrict__ mask, float* __restrict__ bias64,
    float* __restrict__ mask64)
{
  int gid = blockIdx.x * 256 + threadIdx.x;   // 1152 blocks = 294912 = 32768 + 262144
  int p = gid & 4095, i = p >> 6, j = p & 63;
  bool valid = (i < 49) && (j < 49);
  if (gid < 32768) {
    int h = gid >> 12;
    bias64[gid] = valid ? t16[ridx[i * 49 + j] * 8 + h] : 0.f;
  } else {
    int g2 = gid - 32768;
    int w = g2 >> 12;
    mask64[g2] = valid ? mask[w * 2401 + i * 49 + j] : 0.f;
  }
}

// ---------------- QKV GEMM: fp32 A, head-packed d-permuted bf16 output ------
// qkv_p[b][h][s][tok][32] with d' = (quad<<3)+(n4<<2)+r permutation inside each
// 32-block (transparent to attention: Q,K share it; V un-permuted at staging).
// Swapped-operand MFMA: N-dim on quad*4+r axis -> lane packs 8 bf16 = 16B store.
__global__ __launch_bounds__(256) void gemm_qkv(
    const float* __restrict__ X, const unsigned short* __restrict__ W,
    const float* __restrict__ bias, unsigned short* __restrict__ qkv)
{
  __shared__ __align__(1024) unsigned short sA[128 * 64];
  __shared__ __align__(1024) unsigned short sB[128 * 64];
  const int t = threadIdx.x, w = t >> 6, l = t & 63, quad = l >> 4, l15 = l & 15;
  const int idx = blockIdx.x;
  const int x8 = idx & 7, local = idx >> 3;
  const int my = x8 * 98 + local / 6, bnb = local % 6;
  const int bm = my * 128, bn = bnb * 128;
  const int wm = (w >> 1) * 64, wn = (w & 1) * 64;
  const int arow = t >> 1, ahalf = t & 1;    // A staging: 2 threads per row
  const int srow = t >> 3, sch = t & 7;      // B staging (cp16)

  f32x4 acc[4][4] = {};                      // acc[nW][mA]
#pragma unroll 1
  for (int kt = 0; kt < 4; ++kt) {
    const int k0 = kt << 6;
    if (kt) __syncthreads();
#pragma unroll
    for (int i = 0; i < 4; ++i) {            // B: async 16B direct-to-LDS
      const int row = i * 32 + srow;
      const int sc  = sch ^ (srow & 7);
      cp16(W + (size_t)(bn + row) * 256 + k0 + sc * 8, sB + (i * 256 + w * 64) * 8);
    }
    {                                         // A: fp32 -> bf16 -> ds_write_b128
      const float* ap = X + (size_t)(bm + arow) * 256 + k0 + ahalf * 32;
#pragma unroll
      for (int c = 0; c < 4; ++c) {
        float4 f0 = *(const float4*)(ap + c * 8);
        float4 f1 = *(const float4*)(ap + c * 8 + 4);
        uint4 u;
        u.x = f2bf(f0.x) | ((unsigned)f2bf(f0.y) << 16);
        u.y = f2bf(f0.z) | ((unsigned)f2bf(f0.w) << 16);
        u.z = f2bf(f1.x) | ((unsigned)f2bf(f1.y) << 16);
        u.w = f2bf(f1.z) | ((unsigned)f2bf(f1.w) << 16);
        const int cb = ahalf * 4 + c;
        *(uint4*)&sA[arow * 64 + ((cb ^ (arow & 7)) * 8)] = u;
      }
    }
    __syncthreads();
#pragma unroll
    for (int kk = 0; kk < 2; ++kk) {
      bf16x8 xf[4], wf[4];
#pragma unroll
      for (int mt = 0; mt < 4; ++mt)
        xf[mt] = *(const bf16x8*)&sA[(wm + mt * 16 + l15) * 64 + (((4 * kk + quad) ^ (l15 & 7)) * 8)];
#pragma unroll
      for (int nt = 0; nt < 4; ++nt)
        wf[nt] = *(const bf16x8*)&sB[(wn + nt * 16 + l15) * 64 + (((4 * kk + quad) ^ (l15 & 7)) * 8)];
#pragma unroll
      for (int nt = 0; nt < 4; ++nt)
#pragma unroll
        for (int mt = 0; mt < 4; ++mt)
          acc[nt][mt] = __builtin_amdgcn_mfma_f32_16x16x32_bf16(wf[nt], xf[mt], acc[nt][mt], 0, 0, 0);
    }
  }
  // epilogue: lane holds N-cols (quad*4+r); pack pair of 16-tiles -> 16B store
  const int nbase = bn + wn;                 // multiple of 32
#pragma unroll
  for (int mA = 0; mA < 4; ++mA) {
    const int mrow = bm + wm + mA * 16 + l15;
    const unsigned bb = (unsigned)(((unsigned long long)mrow * 87652394ull) >> 32);
    const int tok = mrow - (int)bb * 49;
#pragma unroll
    for (int k = 0; k < 2; ++k) {
      const int n0 = nbase + k * 32;         // 32-block start -> uniform (s,h)
      const int s = n0 >> 8, h = (n0 >> 5) & 7;
      const f32x4 b0 = *(const f32x4*)(bias + n0 + quad * 4);
      const f32x4 b1 = *(const f32x4*)(bias + n0 + 16 + quad * 4);
      const f32x4 a0 = acc[2 * k][mA], a1 = acc[2 * k + 1][mA];
      uint4 u;
      u.x = f2bf(a0[0] + b0[0]) | ((unsigned)f2bf(a0[1] + b0[1]) << 16);
      u.y = f2bf(a0[2] + b0[2]) | ((unsigned)f2bf(a0[3] + b0[3]) << 16);
      u.z = f2bf(a1[0] + b1[0]) | ((unsigned)f2bf(a1[1] + b1[1]) << 16);
      u.w = f2bf(a1[2] + b1[2]) | ((unsigned)f2bf(a1[3] + b1[3]) << 16);
      *(uint4*)(qkv + (size_t)((bb * 8u + h) * 3u + s) * 1568 + tok * 32 + quad * 8) = u;
    }
  }
}

// ---------------- MFMA window attention (head-packed, d-permuted input) -----
__global__ __launch_bounds__(256) void attn2(
    const unsigned short* __restrict__ qkv, const float* __restrict__ logit_scale,
    const float* __restrict__ bias64, const float* __restrict__ mask64,
    unsigned short* __restrict__ aout)
{
  __shared__ __align__(1024) char smem[4 * 12544];
  const int w = threadIdx.x >> 6, l = threadIdx.x & 63, quad = l >> 4, l15 = l & 15;
  const int flat = blockIdx.x * 4 + w;
  const int b = flat >> 3, h = flat & 7;
  char* my = smem + w * 12544;
  unsigned short* vT = (unsigned short*)my;            // [32][64] bf16, swizzled, 4 KB
  unsigned short* P  = (unsigned short*)(my + 4096);   // [64][64] bf16, swizzled, 8 KB
  float* rk = (float*)(my + 12288);                    // 64 f32

  const unsigned short* qb = qkv + (size_t)flat * 4704;
  const unsigned short* kb = qb + 1568;
  const unsigned short* vb = qb + 3136;

  // ---- fragment loads: lane reads 16B at tok*64B + quad*16B (d'-order)
  bf16x8 kf[4], qf[4];
#pragma unroll
  for (int mt = 0; mt < 4; ++mt) kf[mt] = *(const bf16x8*)(kb + (mt * 16 + l15) * 32 + quad * 8);
#pragma unroll
  for (int nt = 0; nt < 4; ++nt) qf[nt] = *(const bf16x8*)(qb + (nt * 16 + l15) * 32 + quad * 8);

  // ---- norms from frags (perm-invariant)
  const float scale = __expf(fminf(logit_scale[h], 4.60517019f));
  float rqv[4];
#pragma unroll
  for (int nt = 0; nt < 4; ++nt) {
    float s = 0.f;
#pragma unroll
    for (int d = 0; d < 8; ++d) { float f = (float)qf[nt][d]; s += f * f; }
    s += __shfl_xor(s, 16, 64); s += __shfl_xor(s, 32, 64);
    rqv[nt] = scale / fmaxf(sqrtf(s), 1e-12f);
  }
#pragma unroll
  for (int mt = 0; mt < 4; ++mt) {
    float s = 0.f;
#pragma unroll
    for (int d = 0; d < 8; ++d) { float f = (float)kf[mt][d]; s += f * f; }
    s += __shfl_xor(s, 16, 64); s += __shfl_xor(s, 32, 64);
    if (quad == 0) rk[mt * 16 + l15] = 1.f / fmaxf(sqrtf(s), 1e-12f);
  }

  // ---- V^T stage, un-permuting d' -> d  (d' = q*8+n4*4+r  =>  d = n4*16+q*4+r)
  if (l < 49) {
    unsigned short vv[32];
#pragma unroll
    for (int c = 0; c < 4; ++c) *(uint4*)&vv[c * 8] = *(const uint4*)(vb + l * 32 + c * 8);
#pragma unroll
    for (int dp = 0; dp < 32; ++dp) {
      const int d = (((dp >> 2) & 1) << 4) + ((dp >> 3) << 2) + (dp & 3);
      vT[d * 64 + (((l >> 3) ^ (d & 7)) << 3) + (l & 7)] = vv[dp];
    }
  } else {
#pragma unroll
    for (int d = 0; d < 32; ++d)
      vT[d * 64 + (((l >> 3) ^ (d & 7)) << 3) + (l & 7)] = 0;
  }
  __syncthreads();

  // ---- S^T[j][i] = K . Q^T (contraction over d', perm-invariant)
  f32x4 acc[4][4] = {};
#pragma unroll
  for (int mt = 0; mt < 4; ++mt)
#pragma unroll
    for (int nt = 0; nt < 4; ++nt)
      acc[mt][nt] = __builtin_amdgcn_mfma_f32_16x16x32_bf16(kf[mt], qf[nt], acc[mt][nt], 0, 0, 0);

  // ---- softmax (token i = nt*16+l15), store P = p/sum to LDS (bf16, swizzled)
  const float* bh = bias64 + (size_t)h * 4096;
  const float* mw = mask64 + (size_t)(b & 63) * 4096;
#pragma unroll
  for (int nt = 0; nt < 4; ++nt) {
    const int i = nt * 16 + l15;
    const float rqi = rqv[nt];
    float s[4][4];
    float mx = -1e30f;
#pragma unroll
    for (int mt = 0; mt < 4; ++mt) {
      const int jb = mt * 16 + quad * 4;
      const f32x4 b4  = *(const f32x4*)(bh + i * 64 + jb);
      const f32x4 m4  = *(const f32x4*)(mw + i * 64 + jb);
      const f32x4 rk4 = *(const f32x4*)(rk + jb);
#pragma unroll
      for (int r = 0; r < 4; ++r) {
        float sv = acc[mt][nt][r] * (rqi * rk4[r]) + b4[r] + m4[r];
        sv = (jb + r < 49) ? sv : -1e30f;
        s[mt][r] = sv;
        mx = fmaxf(mx, sv);
      }
    }
    mx = fmaxf(mx, __shfl_xor(mx, 16, 64));
    mx = fmaxf(mx, __shfl_xor(mx, 32, 64));
    float sum = 0.f;
    float p[4][4];
#pragma unroll
    for (int mt = 0; mt < 4; ++mt)
#pragma unroll
      for (int r = 0; r < 4; ++r) {
        float pv = __expf(s[mt][r] - mx);
        p[mt][r] = pv; sum += pv;
      }
    sum += __shfl_xor(sum, 16, 64);
    sum += __shfl_xor(sum, 32, 64);
    const float rs = 1.f / sum;
#pragma unroll
    for (int mt = 0; mt < 4; ++mt) {
      unsigned d0 = f2bf(p[mt][0] * rs) | ((unsigned)f2bf(p[mt][1] * rs) << 16);
      unsigned d1 = f2bf(p[mt][2] * rs) | ((unsigned)f2bf(p[mt][3] * rs) << 16);
      const int c = 2 * mt + (quad >> 1);
      uint2 uv; uv.x = d0; uv.y = d1;
      *(uint2*)((char*)P + i * 128 + ((c ^ (i & 7)) * 16) + (quad & 1) * 8) = uv;
    }
  }
  __syncthreads();

  // ---- O^T[d][i] = V^T . P^T
  f32x4 oacc[2][4] = {};
#pragma unroll
  for (int kk = 0; kk < 2; ++kk) {
    bf16x8 vf[2], pf[4];
#pragma unroll
    for (int mt = 0; mt < 2; ++mt)
      vf[mt] = *(const bf16x8*)((char*)vT + (mt * 16 + l15) * 128 + (((4 * kk + quad) ^ (l15 & 7)) * 16));
#pragma unroll
    for (int nt = 0; nt < 4; ++nt)
      pf[nt] = *(const bf16x8*)((char*)P + (nt * 16 + l15) * 128 + (((4 * kk + quad) ^ (l15 & 7)) * 16));
#pragma unroll
    for (int mt = 0; mt < 2; ++mt)
#pragma unroll
      for (int nt = 0; nt < 4; ++nt)
        oacc[mt][nt] = __builtin_amdgcn_mfma_f32_16x16x32_bf16(vf[mt], pf[nt], oacc[mt][nt], 0, 0, 0);
  }

  // ---- store O (col=token=l15+16nt, row=d=quad*4+r+16mt)
#pragma unroll
  for (int nt = 0; nt < 4; ++nt) {
    const int tok = nt * 16 + l15;
    if (tok < 49) {
      unsigned short* op = aout + (size_t)(b * 49 + tok) * 256 + h * 32;
#pragma unroll
      for (int mt = 0; mt < 2; ++mt) {
        unsigned u0 = f2bf(oacc[mt][nt][0]) | ((unsigned)f2bf(oacc[mt][nt][1]) << 16);
        unsigned u1 = f2bf(oacc[mt][nt][2]) | ((unsigned)f2bf(oacc[mt][nt][3]) << 16);
        uint2 uv; uv.x = u0; uv.y = u1;
        *(uint2*)(op + mt * 16 + quad * 4) = uv;
      }
    }
  }
}

// ---------------- proj GEMM: bf16 A/W, fp32 out, packed f32x4 stores --------
__global__ __launch_bounds__(256) void gemm_proj(
    const unsigned short* __restrict__ A, const unsigned short* __restrict__ W,
    const float* __restrict__ bias, float* __restrict__ Y)
{
  __shared__ __align__(1024) unsigned short sA[128 * 64];
  __shared__ __align__(1024) unsigned short sB[128 * 64];
  const int t = threadIdx.x, w = t >> 6, l = t & 63, quad = l >> 4, l15 = l & 15;
  const int bm = blockIdx.y * 128, bn = blockIdx.x * 128;
  const int wm = (w >> 1) * 64, wn = (w & 1) * 64;
  const int srow = t >> 3, sch = t & 7;

  f32x4 acc[4][4] = {};                      // acc[nW][mA]
  for (int kt = 0; kt < 4; ++kt) {
    const int k0 = kt << 6;
    if (kt) __syncthreads();
#pragma unroll
    for (int i = 0; i < 4; ++i) {
      const int row = i * 32 + srow;
      const int sc  = sch ^ (srow & 7);
      cp16(A + (size_t)(bm + row) * 256 + k0 + sc * 8, sA + (i * 256 + w * 64) * 8);
      cp16(W + (size_t)(bn + row) * 256 + k0 + sc * 8, sB + (i * 256 + w * 64) * 8);
    }
    __syncthreads();
#pragma unroll
    for (int kk = 0; kk < 2; ++kk) {
      bf16x8 xf[4], wf[4];
#pragma unroll
      for (int mt = 0; mt < 4; ++mt)
        xf[mt] = *(const bf16x8*)&sA[(wm + mt * 16 + l15) * 64 + (((4 * kk + quad) ^ (l15 & 7)) * 8)];
#pragma unroll
      for (int nt = 0; nt < 4; ++nt)
        wf[nt] = *(const bf16x8*)&sB[(wn + nt * 16 + l15) * 64 + (((4 * kk + quad) ^ (l15 & 7)) * 8)];
#pragma unroll
      for (int nt = 0; nt < 4; ++nt)
#pragma unroll
        for (int mt = 0; mt < 4; ++mt)
          acc[nt][mt] = __builtin_amdgcn_mfma_f32_16x16x32_bf16(wf[nt], xf[mt], acc[nt][mt], 0, 0, 0);
    }
  }
  // epilogue: lane holds 4 consecutive cols -> f32x4 16B stores
#pragma unroll
  for (int mA = 0; mA < 4; ++mA) {
    const int row = bm + wm + mA * 16 + l15;
    float* orow = Y + (size_t)row * 256;
#pragma unroll
    for (int nW = 0; nW < 4; ++nW) {
      const int c0 = bn + wn + nW * 16 + quad * 4;
      const f32x4 bv = *(const f32x4*)(bias + c0);
      f32x4 v = acc[nW][mA];
      v[0] += bv[0]; v[1] += bv[1]; v[2] += bv[2]; v[3] += bv[3];
      *(f32x4*)(orow + c0) = v;
    }
  }
}

// ---------------------------------------------------------------------------
extern "C" void kernel_launch(void* const* d_in, const int* in_sizes, int n_in,
                              void* d_out, int out_size, void* d_ws, size_t ws_size,
                              hipStream_t stream) {
  const float* x           = (const float*)d_in[0];
  const float* mask        = (const float*)d_in[1];
  const float* qkv_w       = (const float*)d_in[2];
  const float* q_bias      = (const float*)d_in[3];
  const float* v_bias      = (const float*)d_in[4];
  const float* logit_scale = (const float*)d_in[5];
  const float* cpb_w1      = (const float*)d_in[6];
  const float* cpb_b1      = (const float*)d_in[7];
  const float* cpb_w2      = (const float*)d_in[8];
  const float* proj_w      = (const float*)d_in[9];
  const float* proj_b      = (const float*)d_in[10];
  const float* rel_tab     = (const float*)d_in[11];
  const int*   rel_idx     = (const int*)d_in[12];
  float*       out         = (float*)d_out;

  char* ws = (char*)d_ws;
  unsigned short* qkvp    = (unsigned short*)(ws + 0);          // 154140672 (head-packed)
  unsigned short* aows    = (unsigned short*)(ws + 154140672);  // 51380224
  unsigned short* wq      = (unsigned short*)(ws + 205520896);  // 393216
  unsigned short* wp      = (unsigned short*)(ws + 205914112);  // 131072
  float*          qkvb    = (float*)(ws + 206045184);           // 3072
  float*          table16 = (float*)(ws + 206048256);           // 5632
  float*          bias64  = (float*)(ws + 206053888);           // 131072
  float*          mask64  = (float*)(ws + 206184960);           // 1048576
  // end: 207233536

  prep_kernel<<<1024, 256, 0, stream>>>(qkv_w, proj_w, q_bias, v_bias, wq, wp, qkvb);
  cpb_mlp<<<169, 64, 0, stream>>>(rel_tab, cpb_w1, cpb_b1, cpb_w2, table16);
  bmb<<<1152, 256, 0, stream>>>(table16, rel_idx, mask, bias64, mask64);
  gemm_qkv<<<4704, 256, 0, stream>>>(x, wq, qkvb, qkvp);
  attn2<<<4096, 256, 0, stream>>>(qkvp, logit_scale, bias64, mask64, aows);
  gemm_proj<<<dim3(2, 784), 256, 0, stream>>>(aows, wp, proj_b, out);
}